// Round 6
// baseline (821.393 us; speedup 1.0000x reference)
//
#include <hip/hip_runtime.h>

#define N_NODES 50000
#define N_EDGES 1600000
#define IN_FEATS 128
#define N_HIDDEN 256
#define N_CLASSES 41
#define CHW 16                 // chunk width (floats) = 64 B
#define NCHUNK0 8              // 128/16
#define NCHUNK1 3              // 48/16
#define NB_G 782               // ceil(50000/64)
#define ECAP 1024

typedef float vf4 __attribute__((ext_vector_type(4)));   // native vector for nt store

// -------- workspace layout (bytes), total 32,614,400 (proven to fit, round 4) ----
#define IDEG_OFF 0             // N_NODES int
#define ROWS_OFF 204800        // N_NODES+1 int
#define CURS_OFF 409600        // N_NODES int
#define ESRC_OFF 614400        // N_EDGES int (6.4 MB)
#define ACC0_OFF 7014400       // [8][N_NODES][16] f32 (25.6 MB); y1 aliases chunks 0..2

__global__ void deg_kernel(const int* __restrict__ dst, int* __restrict__ ideg) {
    int e = blockIdx.x * blockDim.x + threadIdx.x;
    if (e < N_EDGES) atomicAdd(&ideg[dst[e]], 1);
}

#define SCAN_THREADS 1024
#define SCAN_CHUNK ((N_NODES + SCAN_THREADS - 1) / SCAN_THREADS)   // 49
__global__ __launch_bounds__(SCAN_THREADS) void scan_kernel(
        const int* __restrict__ ideg, int* __restrict__ row_start,
        int* __restrict__ cursor) {
    __shared__ int part[SCAN_THREADS];
    int t = threadIdx.x;
    int lo = t * SCAN_CHUNK;
    int hi = min(lo + SCAN_CHUNK, N_NODES);
    int s = 0;
    for (int i = lo; i < hi; ++i) s += ideg[i];
    part[t] = s;
    __syncthreads();
    for (int off = 1; off < SCAN_THREADS; off <<= 1) {
        int v = (t >= off) ? part[t - off] : 0;
        __syncthreads();
        if (t >= off) part[t] += v;
        __syncthreads();
    }
    int run = (t == 0) ? 0 : part[t - 1];
    for (int i = lo; i < hi; ++i) {
        row_start[i] = run;
        cursor[i] = run;
        run += ideg[i];
    }
    if (t == SCAN_THREADS - 1) row_start[N_NODES] = part[SCAN_THREADS - 1];
}

__global__ void fill_csr(const int* __restrict__ src, const int* __restrict__ dst,
                         int* __restrict__ cursor, int* __restrict__ edge_src) {
    int e = blockIdx.x * blockDim.x + threadIdx.x;
    if (e >= N_EDGES) return;
    int d = dst[e];
    int p = atomicAdd(&cursor[d], 1);
    edge_src[p] = src[e];
}

// repack one 16-float column chunk contiguously into pbuf (= d_out scratch)
__global__ void repack_chunk(const float* __restrict__ feat, int c,
                             float* __restrict__ pbuf) {
    int p = blockIdx.x * 256 + threadIdx.x;      // < 800000
    int n = p >> 4, j = p & 15;
    pbuf[p] = feat[(size_t)n * IN_FEATS + c * CHW + j];
}

// gather one chunk for 64 nodes/block: wave = 16 nodes x 4 lanes (float4/lane)
__global__ __launch_bounds__(256) void gather0(
        const float* __restrict__ pbuf, int chunk,
        const int* __restrict__ row_start, const int* __restrict__ edge_src,
        float* __restrict__ acc0) {
    __shared__ int eidx[4][ECAP];
    const int t = threadIdx.x;
    const int w = t >> 6, lane = t & 63;
    const int g = lane >> 2, l4 = lane & 3;
    const int n0w = blockIdx.x * 64 + w * 16;

    int v = row_start[min(n0w + lane, N_NODES)];
    const int gbase = __shfl(v, 0);
    const int sg = __shfl(v, g);
    const int cnt = __shfl(v, g + 1) - sg;
    const int sl = sg - gbase;
    const int tot = __shfl(v, 16) - gbase;

    for (int i = lane; i < min(tot, ECAP); i += 64)
        eidx[w][i] = __builtin_nontemporal_load(&edge_src[gbase + i]);
    __syncthreads();

    int maxc = cnt;
#pragma unroll
    for (int off = 32; off; off >>= 1) maxc = max(maxc, __shfl_xor(maxc, off));

    const float* fp = pbuf + l4 * 4;
    float4 a0 = make_float4(0.f, 0.f, 0.f, 0.f);
    float4 a1 = make_float4(0.f, 0.f, 0.f, 0.f);
    for (int k = 0; k < maxc; k += 2) {
        if (k < cnt) {
            int p = sl + k;
            int idx = (p < ECAP) ? eidx[w][p]
                                 : __builtin_nontemporal_load(&edge_src[gbase + p]);
            float4 vv = *(const float4*)(fp + (size_t)idx * CHW);
            a0.x += vv.x; a0.y += vv.y; a0.z += vv.z; a0.w += vv.w;
        }
        if (k + 1 < cnt) {
            int p = sl + k + 1;
            int idx = (p < ECAP) ? eidx[w][p]
                                 : __builtin_nontemporal_load(&edge_src[gbase + p]);
            float4 vv = *(const float4*)(fp + (size_t)idx * CHW);
            a1.x += vv.x; a1.y += vv.y; a1.z += vv.z; a1.w += vv.w;
        }
    }
    a0.x += a1.x; a0.y += a1.y; a0.z += a1.z; a0.w += a1.w;
    const int node = n0w + g;
    if (node < N_NODES) {
        vf4 sv = {a0.x, a0.y, a0.z, a0.w};
        __builtin_nontemporal_store(sv,
            (vf4*)(acc0 + ((size_t)chunk * N_NODES + node) * CHW + l4 * 4));
    }
}

// fused MLP: x = acc0/deg -> h = relu(x@W1+b1) (LDS) -> y1 = h@W2 (chunk-major)
// 64 nodes/block; GEMM1 thread tile 16 nodes x 4 units; GEMM2 4 nodes x 3 classes
__global__ __launch_bounds__(256, 1) void mlp_fused(
        const float* __restrict__ acc0, const int* __restrict__ ideg,
        const float* __restrict__ W1, const float* __restrict__ b1,
        const float* __restrict__ W2, float* __restrict__ y1) {
    __shared__ float pool[12480];      // xs[64][128] + ws1[16][256] ; later w2t[48][260]
    __shared__ float hs[64][260];
    __shared__ float sinv[64];
    float* xs  = pool;                 // [64][128]
    float* ws1 = pool + 8192;          // [16][256]

    const int t = threadIdx.x;
    const int node0 = blockIdx.x * 64;

    if (t < 64) {
        int n = node0 + t;
        sinv[t] = (n < N_NODES) ? 1.0f / fmaxf((float)ideg[n], 1.0f) : 0.0f;
    }
    __syncthreads();

    // stage xs (chunk-major acc0 -> node-major), 8192 floats
    for (int r = 0; r < 32; ++r) {
        int p = r * 256 + t;
        int nl = p >> 7, f = p & 127;
        int c = f >> 4, j = f & 15;
        int n = node0 + nl;
        float v = (n < N_NODES) ? acc0[((size_t)c * N_NODES + n) * CHW + j] : 0.0f;
        xs[nl * 128 + f] = v * sinv[nl];
    }

    // prefetch W1 slice 0 (16k x 256 = 4096 floats; 4 float4/thread)
    float4 pf[4];
    {
        const float4* wp = (const float4*)W1;
#pragma unroll
        for (int q = 0; q < 4; ++q) pf[q] = wp[q * 256 + t];
    }
    __syncthreads();
#pragma unroll
    for (int q = 0; q < 4; ++q) ((float4*)ws1)[q * 256 + t] = pf[q];
    __syncthreads();

    // ---- GEMM1 ----
    const int ucol = t & 63;           // units 4*ucol..+3
    const int ng   = t >> 6;           // nodes ng*16..+15
    const int u0   = ucol * 4;
    float acc[16][4];
    {
        float4 bb = *(const float4*)&b1[u0];
#pragma unroll
        for (int nl = 0; nl < 16; ++nl) {
            acc[nl][0] = bb.x; acc[nl][1] = bb.y;
            acc[nl][2] = bb.z; acc[nl][3] = bb.w;
        }
    }
    for (int s = 0; s < 8; ++s) {
        if (s < 7) {
            const float4* wp = (const float4*)(W1 + (s + 1) * 16 * 256);
#pragma unroll
            for (int q = 0; q < 4; ++q) pf[q] = wp[q * 256 + t];
        }
#pragma unroll
        for (int kk = 0; kk < 16; kk += 4) {
            float4 B0 = *(const float4*)&ws1[(kk + 0) * 256 + u0];
            float4 B1 = *(const float4*)&ws1[(kk + 1) * 256 + u0];
            float4 B2 = *(const float4*)&ws1[(kk + 2) * 256 + u0];
            float4 B3 = *(const float4*)&ws1[(kk + 3) * 256 + u0];
#pragma unroll
            for (int nl = 0; nl < 16; ++nl) {
                float4 A = *(const float4*)&xs[(ng * 16 + nl) * 128 + s * 16 + kk];
                acc[nl][0] = fmaf(A.x, B0.x, acc[nl][0]);
                acc[nl][0] = fmaf(A.y, B1.x, acc[nl][0]);
                acc[nl][0] = fmaf(A.z, B2.x, acc[nl][0]);
                acc[nl][0] = fmaf(A.w, B3.x, acc[nl][0]);
                acc[nl][1] = fmaf(A.x, B0.y, acc[nl][1]);
                acc[nl][1] = fmaf(A.y, B1.y, acc[nl][1]);
                acc[nl][1] = fmaf(A.z, B2.y, acc[nl][1]);
                acc[nl][1] = fmaf(A.w, B3.y, acc[nl][1]);
                acc[nl][2] = fmaf(A.x, B0.z, acc[nl][2]);
                acc[nl][2] = fmaf(A.y, B1.z, acc[nl][2]);
                acc[nl][2] = fmaf(A.z, B2.z, acc[nl][2]);
                acc[nl][2] = fmaf(A.w, B3.z, acc[nl][2]);
                acc[nl][3] = fmaf(A.x, B0.w, acc[nl][3]);
                acc[nl][3] = fmaf(A.y, B1.w, acc[nl][3]);
                acc[nl][3] = fmaf(A.z, B2.w, acc[nl][3]);
                acc[nl][3] = fmaf(A.w, B3.w, acc[nl][3]);
            }
        }
        __syncthreads();
        if (s < 7) {
#pragma unroll
            for (int q = 0; q < 4; ++q) ((float4*)ws1)[q * 256 + t] = pf[q];
        }
        __syncthreads();
    }
    // relu -> hs
#pragma unroll
    for (int nl = 0; nl < 16; ++nl) {
        float4 h4 = make_float4(fmaxf(acc[nl][0], 0.f), fmaxf(acc[nl][1], 0.f),
                                fmaxf(acc[nl][2], 0.f), fmaxf(acc[nl][3], 0.f));
        *(float4*)&hs[ng * 16 + nl][u0] = h4;
    }
    __syncthreads();

    // ---- stage W2 transposed into pool (xs/ws1 dead): w2t[48][260] ----
    float* w2t = pool;
    for (int p = t; p < 48 * 256; p += 256) {
        int u = p >> 8, k = p & 255;
        w2t[u * 260 + k] = (u < N_CLASSES) ? W2[k * N_CLASSES + u] : 0.0f;
    }
    __syncthreads();

    // ---- GEMM2 ----
    const int ucol2 = t & 15;          // classes 3*ucol2..+2
    const int ng2   = t >> 4;          // nodes ng2*4..+3
    const int c0 = ucol2 * 3;
    float y[4][3];
#pragma unroll
    for (int i = 0; i < 4; ++i)
#pragma unroll
        for (int j = 0; j < 3; ++j) y[i][j] = 0.f;
    for (int k = 0; k < 256; k += 4) {
        float4 Bp[3];
#pragma unroll
        for (int j = 0; j < 3; ++j) Bp[j] = *(const float4*)&w2t[(c0 + j) * 260 + k];
#pragma unroll
        for (int i = 0; i < 4; ++i) {
            float4 A = *(const float4*)&hs[ng2 * 4 + i][k];
#pragma unroll
            for (int j = 0; j < 3; ++j) {
                y[i][j] = fmaf(A.x, Bp[j].x, y[i][j]);
                y[i][j] = fmaf(A.y, Bp[j].y, y[i][j]);
                y[i][j] = fmaf(A.z, Bp[j].z, y[i][j]);
                y[i][j] = fmaf(A.w, Bp[j].w, y[i][j]);
            }
        }
    }
#pragma unroll
    for (int i = 0; i < 4; ++i) {
        int n = node0 + ng2 * 4 + i;
        if (n < N_NODES) {
#pragma unroll
            for (int j = 0; j < 3; ++j) {
                int u = c0 + j;                       // < 48
                int c = u >> 4, jj = u & 15;
                y1[((size_t)c * N_NODES + n) * CHW + jj] = y[i][j];
            }
        }
    }
}

// second aggregation over chunk-major y1; epilogue /deg + b2
__global__ __launch_bounds__(256) void gather1(
        const float* __restrict__ y1, int chunk,
        const int* __restrict__ row_start, const int* __restrict__ edge_src,
        const float* __restrict__ b2, float* __restrict__ out) {
    __shared__ int eidx[4][ECAP];
    const int t = threadIdx.x;
    const int w = t >> 6, lane = t & 63;
    const int g = lane >> 2, l4 = lane & 3;
    const int n0w = blockIdx.x * 64 + w * 16;

    int v = row_start[min(n0w + lane, N_NODES)];
    const int gbase = __shfl(v, 0);
    const int sg = __shfl(v, g);
    const int cnt = __shfl(v, g + 1) - sg;
    const int sl = sg - gbase;
    const int tot = __shfl(v, 16) - gbase;

    for (int i = lane; i < min(tot, ECAP); i += 64)
        eidx[w][i] = __builtin_nontemporal_load(&edge_src[gbase + i]);
    __syncthreads();

    int maxc = cnt;
#pragma unroll
    for (int off = 32; off; off >>= 1) maxc = max(maxc, __shfl_xor(maxc, off));

    const float* fp = y1 + (size_t)chunk * N_NODES * CHW + l4 * 4;
    float4 a0 = make_float4(0.f, 0.f, 0.f, 0.f);
    float4 a1 = make_float4(0.f, 0.f, 0.f, 0.f);
    for (int k = 0; k < maxc; k += 2) {
        if (k < cnt) {
            int p = sl + k;
            int idx = (p < ECAP) ? eidx[w][p]
                                 : __builtin_nontemporal_load(&edge_src[gbase + p]);
            float4 vv = *(const float4*)(fp + (size_t)idx * CHW);
            a0.x += vv.x; a0.y += vv.y; a0.z += vv.z; a0.w += vv.w;
        }
        if (k + 1 < cnt) {
            int p = sl + k + 1;
            int idx = (p < ECAP) ? eidx[w][p]
                                 : __builtin_nontemporal_load(&edge_src[gbase + p]);
            float4 vv = *(const float4*)(fp + (size_t)idx * CHW);
            a1.x += vv.x; a1.y += vv.y; a1.z += vv.z; a1.w += vv.w;
        }
    }
    const int node = n0w + g;
    if (node < N_NODES) {
        float invd = 1.0f / fmaxf((float)cnt, 1.0f);
        float r[4] = {a0.x + a1.x, a0.y + a1.y, a0.z + a1.z, a0.w + a1.w};
        const int cbase = chunk * CHW + l4 * 4;
#pragma unroll
        for (int i = 0; i < 4; ++i) {
            int col = cbase + i;
            if (col < N_CLASSES)
                out[(size_t)node * N_CLASSES + col] = r[i] * invd + b2[col];
        }
    }
}

extern "C" void kernel_launch(void* const* d_in, const int* in_sizes, int n_in,
                              void* d_out, int out_size, void* d_ws, size_t ws_size,
                              hipStream_t stream) {
    const float* feat = (const float*)d_in[0];
    const int*   src  = (const int*)d_in[1];
    const int*   dst  = (const int*)d_in[2];
    const float* W1   = (const float*)d_in[3];
    const float* b1   = (const float*)d_in[4];
    const float* W2   = (const float*)d_in[5];
    const float* b2   = (const float*)d_in[6];
    float* out = (float*)d_out;

    char* ws = (char*)d_ws;
    int*   ideg      = (int*)(ws + IDEG_OFF);
    int*   row_start = (int*)(ws + ROWS_OFF);
    int*   cursor    = (int*)(ws + CURS_OFF);
    int*   edge_src  = (int*)(ws + ESRC_OFF);
    float* acc0      = (float*)(ws + ACC0_OFF);
    float* y1        = acc0;            // y1 aliases acc0 chunks 0..2
    float* pbuf      = out;             // 3.2 MB scratch inside d_out (dead until gather1)

    hipMemsetAsync(ideg, 0, N_NODES * 4, stream);
    deg_kernel<<<(N_EDGES + 255) / 256, 256, 0, stream>>>(dst, ideg);
    scan_kernel<<<1, SCAN_THREADS, 0, stream>>>(ideg, row_start, cursor);
    fill_csr<<<(N_EDGES + 255) / 256, 256, 0, stream>>>(src, dst, cursor, edge_src);

    for (int c = 0; c < NCHUNK0; ++c) {
        repack_chunk<<<(N_NODES * CHW) / 256, 256, 0, stream>>>(feat, c, pbuf);
        gather0<<<NB_G, 256, 0, stream>>>(pbuf, c, row_start, edge_src, acc0);
    }

    mlp_fused<<<NB_G, 256, 0, stream>>>(acc0, ideg, W1, b1, W2, y1);

    for (int c = 0; c < NCHUNK1; ++c)
        gather1<<<NB_G, 256, 0, stream>>>(y1, c, row_start, edge_src, b2, out);
}

// Round 7
// 478.616 us; speedup vs baseline: 1.7162x; 1.7162x over previous
//
#include <hip/hip_runtime.h>

#define N_NODES 50000
#define N_EDGES 1600000
#define IN_FEATS 128
#define N_HIDDEN 256
#define N_CLASSES 41
#define CHW 16                 // y1 chunk width (floats) = 64 B
#define NCHUNK1 3
#define NB_G 782               // ceil(50000/64) for gather1
#define ECAP 1024
#define NPB 8                  // nodes per block in agg0_mlp

// -------- workspace layout (bytes), ~22.8 MB (proven fit) --------
#define IDEG_OFF 0             // N_NODES int
#define ROWS_OFF 204800        // N_NODES+1 int
#define RANK_OFF 409600        // N_EDGES int (6.4 MB)
#define ESRC_OFF 6809600       // N_EDGES int (6.4 MB)
#define Y1_OFF   13209600      // [3][N_NODES][16] f32 (9.6 MB)

// pass 1: degree count + per-edge rank within its dst bucket
__global__ void deg_rank(const int* __restrict__ dst, int* __restrict__ ideg,
                         int* __restrict__ rank) {
    int e = blockIdx.x * blockDim.x + threadIdx.x;
    if (e < N_EDGES) rank[e] = atomicAdd(&ideg[dst[e]], 1);
}

#define SCAN_THREADS 1024
#define SCAN_CHUNK ((N_NODES + SCAN_THREADS - 1) / SCAN_THREADS)   // 49
__global__ __launch_bounds__(SCAN_THREADS) void scan_kernel(
        const int* __restrict__ ideg, int* __restrict__ row_start) {
    __shared__ int part[SCAN_THREADS];
    int t = threadIdx.x;
    int lo = t * SCAN_CHUNK;
    int hi = min(lo + SCAN_CHUNK, N_NODES);
    int s = 0;
    for (int i = lo; i < hi; ++i) s += ideg[i];
    part[t] = s;
    __syncthreads();
    for (int off = 1; off < SCAN_THREADS; off <<= 1) {
        int v = (t >= off) ? part[t - off] : 0;
        __syncthreads();
        if (t >= off) part[t] += v;
        __syncthreads();
    }
    int run = (t == 0) ? 0 : part[t - 1];
    for (int i = lo; i < hi; ++i) {
        row_start[i] = run;
        run += ideg[i];
    }
    if (t == SCAN_THREADS - 1) row_start[N_NODES] = part[SCAN_THREADS - 1];
}

// pass 2: place edges without cursor atomics
__global__ void fill2(const int* __restrict__ src, const int* __restrict__ dst,
                      const int* __restrict__ rank, const int* __restrict__ row_start,
                      int* __restrict__ edge_src) {
    int e = blockIdx.x * blockDim.x + threadIdx.x;
    if (e >= N_EDGES) return;
    edge_src[row_start[dst[e]] + rank[e]] = src[e];
}

// fused: 8 nodes/block (one wave gathers per node), then relu(x@W1+b1)@W2
// -> y1 chunk-major [3][N][16] (b2 deferred to gather1)
__global__ __launch_bounds__(512) void agg0_mlp(
        const float* __restrict__ feat, const int* __restrict__ row_start,
        const int* __restrict__ edge_src,
        const float* __restrict__ W1, const float* __restrict__ b1,
        const float* __restrict__ W2, float* __restrict__ y1) {
    __shared__ float xs[NPB][IN_FEATS];
    __shared__ float hs[NPB][N_HIDDEN];
    const int t = threadIdx.x;
    const int wave = t >> 6, lane = t & 63;
    const int half = lane >> 5, l31 = lane & 31;
    const int node = blockIdx.x * NPB + wave;

    const int start = row_start[node];
    const int deg = row_start[node + 1] - start;

    // ---- gather: 2 edges/iter (half-wave each, float4/lane), 8 loads in flight ----
    float4 acc = make_float4(0.f, 0.f, 0.f, 0.f);
    for (int base = 0; base < deg; base += 64) {
        int cnt = deg - base; if (cnt > 64) cnt = 64;
        int myIdx = 0;
        if (lane < cnt) myIdx = edge_src[start + base + lane];   // coalesced batch
        for (int j = 0; j < cnt; j += 8) {
#pragma unroll
            for (int u = 0; u < 4; ++u) {
                int e = j + 2 * u + half;
                int sn = __shfl(myIdx, e);
                if (e < cnt) {
                    const float4 v = *(const float4*)(feat + ((size_t)sn << 7) + (l31 << 2));
                    acc.x += v.x; acc.y += v.y; acc.z += v.z; acc.w += v.w;
                }
            }
        }
    }
    acc.x += __shfl_xor(acc.x, 32);
    acc.y += __shfl_xor(acc.y, 32);
    acc.z += __shfl_xor(acc.z, 32);
    acc.w += __shfl_xor(acc.w, 32);
    if (half == 0) {
        float invd = 1.0f / fmaxf((float)deg, 1.0f);
        float4* xp = (float4*)&xs[wave][l31 << 2];
        *xp = make_float4(acc.x * invd, acc.y * invd, acc.z * invd, acc.w * invd);
    }
    __syncthreads();

    // ---- GEMM1: thread owns hidden unit (t&255) for 4 nodes ----
    const int unit = t & 255;
    const int g = (t >> 8) << 2;          // 0 or 4
    float c0 = b1[unit];
    float c1 = c0, c2 = c0, c3 = c0;
#pragma unroll 8
    for (int k = 0; k < IN_FEATS; ++k) {
        float w = W1[k * N_HIDDEN + unit];
        c0 = fmaf(xs[g + 0][k], w, c0);
        c1 = fmaf(xs[g + 1][k], w, c1);
        c2 = fmaf(xs[g + 2][k], w, c2);
        c3 = fmaf(xs[g + 3][k], w, c3);
    }
    hs[g + 0][unit] = fmaxf(c0, 0.f);
    hs[g + 1][unit] = fmaxf(c1, 0.f);
    hs[g + 2][unit] = fmaxf(c2, 0.f);
    hs[g + 3][unit] = fmaxf(c3, 0.f);
    __syncthreads();

    // ---- GEMM2: threads 0..327 -> (node n, class c); write chunk-major ----
    if (t < NPB * N_CLASSES) {
        int n = t / N_CLASSES;
        int c = t - n * N_CLASSES;
        float s = 0.f;
#pragma unroll 8
        for (int k = 0; k < N_HIDDEN; ++k)
            s = fmaf(hs[n][k], W2[k * N_CLASSES + c], s);
        int nd = blockIdx.x * NPB + n;
        y1[((size_t)(c >> 4) * N_NODES + nd) * CHW + (c & 15)] = s;
    } else if (t < NPB * N_CLASSES + NPB * 7) {
        // zero the pad columns 41..47 (chunk 2 tail) so gather1 reads clean data
        int idx = t - NPB * N_CLASSES;
        int n = idx / 7, c = N_CLASSES + idx % 7;
        int nd = blockIdx.x * NPB + n;
        y1[((size_t)(c >> 4) * N_NODES + nd) * CHW + (c & 15)] = 0.0f;
    }
}

// second aggregation over chunk-major y1 (3.2 MB chunk, L2-resident); /deg + b2
__global__ __launch_bounds__(256) void gather1(
        const float* __restrict__ y1, int chunk,
        const int* __restrict__ row_start, const int* __restrict__ edge_src,
        const float* __restrict__ b2, float* __restrict__ out) {
    __shared__ int eidx[4][ECAP];
    const int t = threadIdx.x;
    const int w = t >> 6, lane = t & 63;
    const int g = lane >> 2, l4 = lane & 3;
    const int n0w = blockIdx.x * 64 + w * 16;

    int v = row_start[min(n0w + lane, N_NODES)];
    const int gbase = __shfl(v, 0);
    const int sg = __shfl(v, g);
    const int cnt = __shfl(v, g + 1) - sg;
    const int sl = sg - gbase;
    const int tot = __shfl(v, 16) - gbase;

    for (int i = lane; i < min(tot, ECAP); i += 64)
        eidx[w][i] = edge_src[gbase + i];
    __syncthreads();

    int maxc = cnt;
#pragma unroll
    for (int off = 32; off; off >>= 1) maxc = max(maxc, __shfl_xor(maxc, off));

    const float* fp = y1 + (size_t)chunk * N_NODES * CHW + l4 * 4;
    float4 a0 = make_float4(0.f, 0.f, 0.f, 0.f);
    float4 a1 = make_float4(0.f, 0.f, 0.f, 0.f);
    for (int k = 0; k < maxc; k += 2) {
        if (k < cnt) {
            int p = sl + k;
            int idx = (p < ECAP) ? eidx[w][p] : edge_src[gbase + p];
            float4 vv = *(const float4*)(fp + (size_t)idx * CHW);
            a0.x += vv.x; a0.y += vv.y; a0.z += vv.z; a0.w += vv.w;
        }
        if (k + 1 < cnt) {
            int p = sl + k + 1;
            int idx = (p < ECAP) ? eidx[w][p] : edge_src[gbase + p];
            float4 vv = *(const float4*)(fp + (size_t)idx * CHW);
            a1.x += vv.x; a1.y += vv.y; a1.z += vv.z; a1.w += vv.w;
        }
    }
    const int node = n0w + g;
    if (node < N_NODES) {
        float invd = 1.0f / fmaxf((float)cnt, 1.0f);
        float r[4] = {a0.x + a1.x, a0.y + a1.y, a0.z + a1.z, a0.w + a1.w};
        const int cbase = chunk * CHW + l4 * 4;
#pragma unroll
        for (int i = 0; i < 4; ++i) {
            int col = cbase + i;
            if (col < N_CLASSES)
                out[(size_t)node * N_CLASSES + col] = r[i] * invd + b2[col];
        }
    }
}

extern "C" void kernel_launch(void* const* d_in, const int* in_sizes, int n_in,
                              void* d_out, int out_size, void* d_ws, size_t ws_size,
                              hipStream_t stream) {
    const float* feat = (const float*)d_in[0];
    const int*   src  = (const int*)d_in[1];
    const int*   dst  = (const int*)d_in[2];
    const float* W1   = (const float*)d_in[3];
    const float* b1   = (const float*)d_in[4];
    const float* W2   = (const float*)d_in[5];
    const float* b2   = (const float*)d_in[6];
    float* out = (float*)d_out;

    char* ws = (char*)d_ws;
    int*   ideg      = (int*)(ws + IDEG_OFF);
    int*   row_start = (int*)(ws + ROWS_OFF);
    int*   rank      = (int*)(ws + RANK_OFF);
    int*   edge_src  = (int*)(ws + ESRC_OFF);
    float* y1        = (float*)(ws + Y1_OFF);

    hipMemsetAsync(ideg, 0, N_NODES * 4, stream);
    deg_rank<<<(N_EDGES + 255) / 256, 256, 0, stream>>>(dst, ideg, rank);
    scan_kernel<<<1, SCAN_THREADS, 0, stream>>>(ideg, row_start);
    fill2<<<(N_EDGES + 255) / 256, 256, 0, stream>>>(src, dst, rank, row_start, edge_src);

    agg0_mlp<<<N_NODES / NPB, 512, 0, stream>>>(feat, row_start, edge_src, W1, b1, W2, y1);

    for (int c = 0; c < NCHUNK1; ++c)
        gather1<<<NB_G, 256, 0, stream>>>(y1, c, row_start, edge_src, b2, out);
}